// Round 14
// baseline (129.274 us; speedup 1.0000x reference)
//
#include <hip/hip_runtime.h>
#include <stdint.h>

#define LOG2E 1.44269504088896340736f

typedef __bf16 bf16x8 __attribute__((ext_vector_type(8)));
typedef float f32x4 __attribute__((ext_vector_type(4)));
typedef float f32x16 __attribute__((ext_vector_type(16)));

static constexpr int Bb = 2, Ss = 2048, Ee = 1024, Hh = 16, Dd = 64;
static constexpr int BSE = Bb * Ss * Ee;   // 4194304

// ws layout (uint16 elements)
static constexpr size_t OFF_QB    = 0;
static constexpr size_t OFF_KB    = 4194304;
static constexpr size_t OFF_VB    = 8388608;
static constexpr size_t OFF_WQKV  = 12582912;  // 3*1024*1024
static constexpr size_t OFF_WOUT  = 15728640;  // 1024*1024
static constexpr size_t OFF_QH    = 16777216;  // [B,H,S,D]
static constexpr size_t OFF_KH    = 20971520;  // [B,H,S,D]
static constexpr size_t OFF_VH    = 25165824;  // [B,H,D,S]  (V^T, written directly by gemm z=2)
static constexpr size_t OFF_OB    = 29360128;  // [B,S,E]

__device__ __forceinline__ uint16_t f32_bf16(float f) {
    uint32_t u = __builtin_bit_cast(uint32_t, f);
    u += 0x7fffu + ((u >> 16) & 1u);   // round-to-nearest-even
    return (uint16_t)(u >> 16);
}

__device__ __forceinline__ uint32_t cvt_pk_bf16(float a, float b) {
    uint32_t r;
    asm("v_cvt_pk_bf16_f32 %0, %1, %2" : "=v"(r) : "v"(a), "v"(b));
    return r;
}

__device__ __forceinline__ void perm32swap(uint32_t& x, uint32_t& y) {
    asm("v_permlane32_swap_b32 %0, %1" : "+v"(x), "+v"(y));
}

// ---------------- fp32 -> bf16 conversion pass (q,k,v,w_in,w_out) ----------------
__global__ __launch_bounds__(256) void cvt_kernel(
    const float* __restrict__ q, const float* __restrict__ k, const float* __restrict__ v,
    const float* __restrict__ w1, const float* __restrict__ w2, uint16_t* __restrict__ ws)
{
    const float* srcs[5] = {q, k, v, w1, w2};
    const int ns4[5] = {BSE/4, BSE/4, BSE/4, (3*Ee*Ee)/4, (Ee*Ee)/4};
    uint16_t* dsts[5] = {ws+OFF_QB, ws+OFF_KB, ws+OFF_VB, ws+OFF_WQKV, ws+OFF_WOUT};
    int z = blockIdx.z;
    int i = blockIdx.x * blockDim.x + threadIdx.x;
    if (i < ns4[z]) {
        float4 f = ((const float4*)srcs[z])[i];
        ushort4 o;
        o.x = f32_bf16(f.x); o.y = f32_bf16(f.y);
        o.z = f32_bf16(f.z); o.w = f32_bf16(f.w);
        ((ushort4*)dsts[z])[i] = o;
    }
}

// ---------------- NT GEMM, BMx128 tile, BK=32, 4 waves ----------------
// MODE 0 (BM=128): C = X W^T; z=0 Q (scaled) -> [B,H,S,D]; z=1 K -> [B,H,S,D];
//         z=2 V -> TRANSPOSED store [B,H,D,S] at OFF_VH (packed uint2, 4 s/store)
//         — replaces the separate vtr kernel; orientation/panels unchanged.
// MODE 1 (BM=64):  C = Ob W_out^T + b -> fp32.
template<int MODE, int BM>
__global__ __launch_bounds__(256) void gemm_nt(
    const uint16_t* __restrict__ Aq, const uint16_t* __restrict__ Ak,
    const uint16_t* __restrict__ Av, const uint16_t* __restrict__ Bw,
    const float* __restrict__ bias, uint16_t* __restrict__ OutB,
    uint16_t* __restrict__ OutVT, float* __restrict__ OutF)
{
    constexpr int K = Ee, N = Ee;
    constexpr int M4 = BM / 32;
    const int tid = threadIdx.x;
    const int l = tid & 63, w = tid >> 6;
    const int wr = w >> 1, wc = w & 1;
    const int z = (MODE == 0) ? blockIdx.z : 0;
    int tm, tn;
    if (MODE == 0) { tm = 4 * blockIdx.x + (blockIdx.y >> 3); tn = blockIdx.y & 7; }
    else           { tm = (blockIdx.y >> 3) * 8 + blockIdx.x; tn = blockIdx.y & 7; }

    const uint16_t* A = (MODE == 0) ? (z == 0 ? Aq : (z == 1 ? Ak : Av)) : Aq;
    const uint16_t* Bp = Bw + (size_t)z * Ee * Ee;
    const float* bp = bias + (size_t)z * Ee;

    __shared__ alignas(16) uint16_t As[BM * 32];
    __shared__ alignas(16) uint16_t Bs[128 * 32];

    f32x4 acc[M4][4] = {};
    const int arow = tm * BM;
    const int bcol = tn * 128;

    for (int kt = 0; kt < K / 32; ++kt) {
        __syncthreads();
        #pragma unroll
        for (int it = 0; it < BM / 64; ++it) {
            int c = tid + it * 256;
            int row = c >> 2, qq = c & 3;
            const uint16_t* ga = A + (size_t)(arow + row) * K + kt * 32 + qq * 8;
            __builtin_amdgcn_global_load_lds(
                (const __attribute__((address_space(1))) void*)ga,
                (__attribute__((address_space(3))) void*)(As + c * 8), 16, 0, 0);
        }
        #pragma unroll
        for (int it = 0; it < 2; ++it) {
            int c = tid + it * 256;
            int row = c >> 2, qq = c & 3;
            const uint16_t* gb = Bp + (size_t)(bcol + row) * K + kt * 32 + qq * 8;
            __builtin_amdgcn_global_load_lds(
                (const __attribute__((address_space(1))) void*)gb,
                (__attribute__((address_space(3))) void*)(Bs + c * 8), 16, 0, 0);
        }
        __syncthreads();
        bf16x8 aF[M4], bF[4];
        #pragma unroll
        for (int m = 0; m < M4; ++m)
            aF[m] = *(const bf16x8*)(As + ((wr * (BM / 2) + m * 16 + (l & 15)) * 32 + (l >> 4) * 8));
        #pragma unroll
        for (int n = 0; n < 4; ++n)
            bF[n] = *(const bf16x8*)(Bs + ((wc * 64 + n * 16 + (l & 15)) * 32 + (l >> 4) * 8));
        #pragma unroll
        for (int m = 0; m < M4; ++m)
            #pragma unroll
            for (int n = 0; n < 4; ++n)
                acc[m][n] = __builtin_amdgcn_mfma_f32_16x16x32_bf16(aF[m], bF[n], acc[m][n], 0, 0, 0);
    }

    #pragma unroll
    for (int n = 0; n < 4; ++n) {
        int col = bcol + wc * 64 + n * 16 + (l & 15);
        float bn = bp[col];
        #pragma unroll
        for (int m = 0; m < M4; ++m) {
            int row0 = arow + wr * (BM / 2) + m * 16 + (l >> 4) * 4;
            if (MODE == 0 && z == 2) {
                // V^T packed store: 4 consecutive s (=row0..row0+3) in one d-row
                int b = row0 >> 11, s = row0 & 2047, hh = col >> 6, d = col & 63;
                uint2 pk;
                pk.x = (uint32_t)f32_bf16(acc[m][n][0] + bn) |
                       ((uint32_t)f32_bf16(acc[m][n][1] + bn) << 16);
                pk.y = (uint32_t)f32_bf16(acc[m][n][2] + bn) |
                       ((uint32_t)f32_bf16(acc[m][n][3] + bn) << 16);
                *(uint2*)&OutVT[((size_t)((b * Hh + hh) * Dd + d)) * Ss + s] = pk;
            } else {
                #pragma unroll
                for (int j = 0; j < 4; ++j) {
                    int row = row0 + j;
                    float v = acc[m][n][j] + bn;
                    if (MODE == 0) {
                        if (z == 0) v *= 0.125f * LOG2E;  // 1/sqrt(D) with log2e folded
                        int b = row >> 11, s = row & 2047, hh = col >> 6, d = col & 63;
                        OutB[(size_t)z * BSE + (size_t)(((b * Hh) + hh) * Ss + s) * Dd + d] = f32_bf16(v);
                    } else {
                        OutF[(size_t)row * N + col] = v;
                    }
                }
            }
        }
    }
}

// ---------------- flash attention: T15 pipeline — QK(t+1) overlaps softmax(t) ----
// Grid 512 = 16 qb x 32 bh (XCD-swizzled) = 2 blocks/CU. 4 waves x 32 q-rows.
// Tri-buffered LDS; per iter: vmcnt(0)+barrier -> stage(t+2) DMA ->
// {build_pb(s_cur) [VALU] || QK(t+1) [MFMA]} -> PV(t).
__global__ __launch_bounds__(256, 2) void attn_kernel(
    const uint16_t* __restrict__ Qh, const uint16_t* __restrict__ Kh,
    const uint16_t* __restrict__ Vtg, uint16_t* __restrict__ Ob)
{
    const int tid = threadIdx.x;
    const int l = tid & 63, w = tid >> 6;
    const int q = l & 31, hi = l >> 5;

    const int orig = blockIdx.x;
    const int L = (orig & 7) * 64 + (orig >> 3);
    const int qb = L & 15, bh = L >> 4;

    const int q0 = qb * 128;
    const size_t baseK = (size_t)bh * Ss * Dd;
    const size_t baseV = (size_t)bh * Dd * Ss;

    __shared__ alignas(16) uint16_t Ks[3][64 * 64];  // [key][d], XOR-swizzled
    __shared__ alignas(16) uint16_t Vt[3][64 * 64];  // [d][key], XOR-swizzled

    bf16x8 qf[4];
    {
        const uint16_t* qp = Qh + baseK + (size_t)(q0 + w * 32 + q) * Dd + hi * 8;
        #pragma unroll
        for (int m = 0; m < 4; ++m) qf[m] = *(const bf16x8*)(qp + 16 * m);
    }

    auto stage = [&](int kt, int buf) {
        const int key0 = kt * 64;
        #pragma unroll
        for (int it = 0; it < 2; ++it) {
            int c = tid + 256 * it, row = c >> 3, cc = c & 7;
            const uint16_t* gk = Kh + baseK + (size_t)(key0 + row) * Dd + ((cc ^ (row & 7)) * 8);
            __builtin_amdgcn_global_load_lds(
                (const __attribute__((address_space(1))) void*)gk,
                (__attribute__((address_space(3))) void*)(&Ks[buf][c * 8]), 16, 0, 0);
        }
        #pragma unroll
        for (int it = 0; it < 2; ++it) {
            int c = tid + 256 * it, d = c >> 3, j = c & 7;
            const uint16_t* gv = Vtg + baseV + (size_t)d * Ss + key0 + 8 * (j ^ (d & 7) ^ (d >> 3));
            __builtin_amdgcn_global_load_lds(
                (const __attribute__((address_space(1))) void*)gv,
                (__attribute__((address_space(3))) void*)(&Vt[buf][c * 8]), 16, 0, 0);
        }
    };

    f32x16 o0 = {}, o1 = {};
    float lsum = 0.f;

    auto qk = [&](int b, f32x16& s0, f32x16& s1) {
        __builtin_amdgcn_s_setprio(1);
        #pragma unroll
        for (int m = 0; m < 4; ++m) {
            int sw = ((2 * m + hi) ^ (q & 7)) << 3;
            bf16x8 k0 = *(const bf16x8*)&Ks[b][q * 64 + sw];
            bf16x8 k1 = *(const bf16x8*)&Ks[b][(32 + q) * 64 + sw];
            s0 = __builtin_amdgcn_mfma_f32_32x32x16_bf16(k0, qf[m], s0, 0, 0, 0);
            s1 = __builtin_amdgcn_mfma_f32_32x32x16_bf16(k1, qf[m], s1, 0, 0, 0);
        }
        __builtin_amdgcn_s_setprio(0);
    };

    auto build_pb = [&](const f32x16& sv, bf16x8* pbout) {
        uint32_t W[4][2];
        #pragma unroll
        for (int a = 0; a < 4; ++a) {
            float p0 = __builtin_amdgcn_exp2f(sv[4 * a + 0]);
            float p1 = __builtin_amdgcn_exp2f(sv[4 * a + 1]);
            float p2 = __builtin_amdgcn_exp2f(sv[4 * a + 2]);
            float p3 = __builtin_amdgcn_exp2f(sv[4 * a + 3]);
            lsum += (p0 + p1) + (p2 + p3);
            W[a][0] = cvt_pk_bf16(p0, p1);
            W[a][1] = cvt_pk_bf16(p2, p3);
        }
        #pragma unroll
        for (int kl = 0; kl < 2; ++kl) {
            uint32_t x0 = W[2 * kl][0], x1 = W[2 * kl][1];
            uint32_t y0 = W[2 * kl + 1][0], y1 = W[2 * kl + 1][1];
            perm32swap(x0, y0);
            perm32swap(x1, y1);
            union { uint32_t u[4]; bf16x8 v; } pu;
            pu.u[0] = x0; pu.u[1] = x1; pu.u[2] = y0; pu.u[3] = y1;
            pbout[kl] = pu.v;
        }
    };

    auto pv = [&](int b, const bf16x8* pb) {
        __builtin_amdgcn_s_setprio(1);
        #pragma unroll
        for (int ka = 0; ka < 4; ++ka) {
            #pragma unroll
            for (int dt = 0; dt < 2; ++dt) {
                int d = 32 * dt + q;
                int swz = (2 * ka + hi) ^ (d & 7) ^ (d >> 3);
                bf16x8 vf = *(const bf16x8*)&Vt[b][d * 64 + swz * 8];
                if (dt == 0)
                    o0 = __builtin_amdgcn_mfma_f32_32x32x16_bf16(vf, pb[ka], o0, 0, 0, 0);
                else
                    o1 = __builtin_amdgcn_mfma_f32_32x32x16_bf16(vf, pb[ka], o1, 0, 0, 0);
            }
        }
        __builtin_amdgcn_s_setprio(0);
    };

    // prologue: tiles 0,1 staged; compute s(0)
    stage(0, 0);
    stage(1, 1);
    f32x16 sc0 = {}, sc1 = {};
    asm volatile("s_waitcnt vmcnt(4)" ::: "memory");   // stage(0) landed
    __builtin_amdgcn_s_barrier();
    __builtin_amdgcn_sched_barrier(0);
    qk(0, sc0, sc1);

    auto body = [&](int kt, int b, int bn, int bs, bool doStage, bool doNext) {
        asm volatile("s_waitcnt vmcnt(0)" ::: "memory");   // stage(kt+1) landed
        __builtin_amdgcn_s_barrier();                      // closes iter kt-1 reads
        __builtin_amdgcn_sched_barrier(0);
        if (doStage) stage(kt + 2, bs);

        bf16x8 pb[4];
        build_pb(sc0, pb + 0);
        build_pb(sc1, pb + 2);

        f32x16 sn0 = {}, sn1 = {};
        if (doNext) qk(bn, sn0, sn1);

        pv(b, pb);
        sc0 = sn0; sc1 = sn1;
    };

    for (int u = 0; u < 30; u += 3) {
        body(u + 0, 0, 1, 2, true, true);
        body(u + 1, 1, 2, 0, true, true);
        body(u + 2, 2, 0, 1, true, true);
    }
    body(30, 0, 1, 0, false, true);
    body(31, 1, 0, 0, false, false);

    // normalize + LDS transpose epilogue (reuse Ks[0..1]: 16 KB [q=128][d=64])
    float lr = lsum + __shfl_xor(lsum, 32);
    const float inv = 1.0f / lr;
    __syncthreads();   // all waves done with tile-31 reads
    uint16_t* Os = &Ks[0][0];
    const int ql = w * 32 + q;
    #pragma unroll
    for (int dt = 0; dt < 2; ++dt) {
        const f32x16& oo = dt ? o1 : o0;
        #pragma unroll
        for (int rr = 0; rr < 16; ++rr) {
            int d = 32 * dt + (rr & 3) + 8 * (rr >> 2) + 4 * hi;
            Os[ql * 64 + (((d >> 3) ^ (ql & 7)) << 3) + (d & 7)] = f32_bf16(oo[rr] * inv);
        }
    }
    __syncthreads();
    const int bq = bh >> 4, hh = bh & 15;
    #pragma unroll
    for (int it = 0; it < 4; ++it) {
        int qr = it * 32 + (tid >> 3);
        int c = tid & 7;
        bf16x8 vv = *(const bf16x8*)&Os[qr * 64 + ((c ^ (qr & 7)) << 3)];
        *(bf16x8*)(Ob + (size_t)(bq * Ss + q0 + qr) * Ee + hh * Dd + c * 8) = vv;
    }
}

extern "C" void kernel_launch(void* const* d_in, const int* in_sizes, int n_in,
                              void* d_out, int out_size, void* d_ws, size_t ws_size,
                              hipStream_t stream) {
    (void)in_sizes; (void)n_in; (void)out_size; (void)ws_size;
    const float* query = (const float*)d_in[0];
    const float* key   = (const float*)d_in[1];
    const float* value = (const float*)d_in[2];
    const float* w_in  = (const float*)d_in[3];
    const float* b_in  = (const float*)d_in[4];
    const float* w_out = (const float*)d_in[5];
    const float* b_out = (const float*)d_in[6];
    uint16_t* ws = (uint16_t*)d_ws;

    uint16_t* qb    = ws + OFF_QB;
    uint16_t* kb    = ws + OFF_KB;
    uint16_t* vb    = ws + OFF_VB;
    uint16_t* wqkvb = ws + OFF_WQKV;
    uint16_t* woutb = ws + OFF_WOUT;
    uint16_t* Qh    = ws + OFF_QH;
    uint16_t* Kh    = ws + OFF_KH;
    uint16_t* Vtg   = ws + OFF_VH;
    uint16_t* Ob    = ws + OFF_OB;

    cvt_kernel<<<dim3(4096, 1, 5), 256, 0, stream>>>(query, key, value, w_in, w_out, ws);
    gemm_nt<0, 128><<<dim3(8, 32, 3), 256, 0, stream>>>(qb, kb, vb, wqkvb, b_in, Qh, Vtg, nullptr);
    attn_kernel<<<dim3(512), 256, 0, stream>>>(Qh, Kh, Vtg, Ob);
    gemm_nt<1, 64><<<dim3(8, 64), 256, 0, stream>>>(Ob, nullptr, nullptr, woutb, b_out, nullptr, nullptr, (float*)d_out);
}

// Round 15
// 119.603 us; speedup vs baseline: 1.0809x; 1.0809x over previous
//
#include <hip/hip_runtime.h>
#include <stdint.h>

#define LOG2E 1.44269504088896340736f

typedef __bf16 bf16x8 __attribute__((ext_vector_type(8)));
typedef float f32x4 __attribute__((ext_vector_type(4)));
typedef float f32x16 __attribute__((ext_vector_type(16)));

static constexpr int Bb = 2, Ss = 2048, Ee = 1024, Hh = 16, Dd = 64;
static constexpr int BSE = Bb * Ss * Ee;   // 4194304

// ws layout (uint16 elements)
static constexpr size_t OFF_QB    = 0;
static constexpr size_t OFF_KB    = 4194304;
static constexpr size_t OFF_VB    = 8388608;
static constexpr size_t OFF_WQKV  = 12582912;  // 3*1024*1024
static constexpr size_t OFF_WOUT  = 15728640;  // 1024*1024
static constexpr size_t OFF_QH    = 16777216;  // [B,H,S,D]
static constexpr size_t OFF_KH    = 20971520;  // [B,H,S,D]
static constexpr size_t OFF_VH    = 25165824;  // [B,H,D,S]  (V transposed, from vtr)
static constexpr size_t OFF_OB    = 29360128;  // [B,S,E]; also z=2 staging [B,H,S,D]
// OFF_OB - OFF_QH = 3*BSE, so gemm<0> writes z=2 at OutB + 3*BSE.

__device__ __forceinline__ uint16_t f32_bf16(float f) {
    uint32_t u = __builtin_bit_cast(uint32_t, f);
    u += 0x7fffu + ((u >> 16) & 1u);   // round-to-nearest-even
    return (uint16_t)(u >> 16);
}

__device__ __forceinline__ uint32_t cvt_pk_bf16(float a, float b) {
    uint32_t r;
    asm("v_cvt_pk_bf16_f32 %0, %1, %2" : "=v"(r) : "v"(a), "v"(b));
    return r;
}

__device__ __forceinline__ void perm32swap(uint32_t& x, uint32_t& y) {
    asm("v_permlane32_swap_b32 %0, %1" : "+v"(x), "+v"(y));
}

// ---------------- fp32 -> bf16 conversion pass (q,k,v,w_in,w_out) ----------------
__global__ __launch_bounds__(256) void cvt_kernel(
    const float* __restrict__ q, const float* __restrict__ k, const float* __restrict__ v,
    const float* __restrict__ w1, const float* __restrict__ w2, uint16_t* __restrict__ ws)
{
    const float* srcs[5] = {q, k, v, w1, w2};
    const int ns4[5] = {BSE/4, BSE/4, BSE/4, (3*Ee*Ee)/4, (Ee*Ee)/4};
    uint16_t* dsts[5] = {ws+OFF_QB, ws+OFF_KB, ws+OFF_VB, ws+OFF_WQKV, ws+OFF_WOUT};
    int z = blockIdx.z;
    int i = blockIdx.x * blockDim.x + threadIdx.x;
    if (i < ns4[z]) {
        float4 f = ((const float4*)srcs[z])[i];
        ushort4 o;
        o.x = f32_bf16(f.x); o.y = f32_bf16(f.y);
        o.z = f32_bf16(f.z); o.w = f32_bf16(f.w);
        ((ushort4*)dsts[z])[i] = o;
    }
}

// ---------------- NT GEMM, BMx128 tile, BK=32, 4 waves ----------------
template<int MODE, int BM>
__global__ __launch_bounds__(256) void gemm_nt(
    const uint16_t* __restrict__ Aq, const uint16_t* __restrict__ Ak,
    const uint16_t* __restrict__ Av, const uint16_t* __restrict__ Bw,
    const float* __restrict__ bias, uint16_t* __restrict__ OutB,
    float* __restrict__ OutF)
{
    constexpr int K = Ee, N = Ee;
    constexpr int M4 = BM / 32;
    const int tid = threadIdx.x;
    const int l = tid & 63, w = tid >> 6;
    const int wr = w >> 1, wc = w & 1;
    const int z = (MODE == 0) ? blockIdx.z : 0;
    int tm, tn;
    if (MODE == 0) { tm = 4 * blockIdx.x + (blockIdx.y >> 3); tn = blockIdx.y & 7; }
    else           { tm = (blockIdx.y >> 3) * 8 + blockIdx.x; tn = blockIdx.y & 7; }

    const uint16_t* A = (MODE == 0) ? (z == 0 ? Aq : (z == 1 ? Ak : Av)) : Aq;
    const uint16_t* Bp = Bw + (size_t)z * Ee * Ee;
    const float* bp = bias + (size_t)z * Ee;
    const size_t zoff = (size_t)(z == 2 ? 3 : z) * BSE;

    __shared__ alignas(16) uint16_t As[BM * 32];
    __shared__ alignas(16) uint16_t Bs[128 * 32];

    f32x4 acc[M4][4] = {};
    const int arow = tm * BM;
    const int bcol = tn * 128;

    for (int kt = 0; kt < K / 32; ++kt) {
        __syncthreads();
        #pragma unroll
        for (int it = 0; it < BM / 64; ++it) {
            int c = tid + it * 256;
            int row = c >> 2, qq = c & 3;
            const uint16_t* ga = A + (size_t)(arow + row) * K + kt * 32 + qq * 8;
            __builtin_amdgcn_global_load_lds(
                (const __attribute__((address_space(1))) void*)ga,
                (__attribute__((address_space(3))) void*)(As + c * 8), 16, 0, 0);
        }
        #pragma unroll
        for (int it = 0; it < 2; ++it) {
            int c = tid + it * 256;
            int row = c >> 2, qq = c & 3;
            const uint16_t* gb = Bp + (size_t)(bcol + row) * K + kt * 32 + qq * 8;
            __builtin_amdgcn_global_load_lds(
                (const __attribute__((address_space(1))) void*)gb,
                (__attribute__((address_space(3))) void*)(Bs + c * 8), 16, 0, 0);
        }
        __syncthreads();
        bf16x8 aF[M4], bF[4];
        #pragma unroll
        for (int m = 0; m < M4; ++m)
            aF[m] = *(const bf16x8*)(As + ((wr * (BM / 2) + m * 16 + (l & 15)) * 32 + (l >> 4) * 8));
        #pragma unroll
        for (int n = 0; n < 4; ++n)
            bF[n] = *(const bf16x8*)(Bs + ((wc * 64 + n * 16 + (l & 15)) * 32 + (l >> 4) * 8));
        #pragma unroll
        for (int m = 0; m < M4; ++m)
            #pragma unroll
            for (int n = 0; n < 4; ++n)
                acc[m][n] = __builtin_amdgcn_mfma_f32_16x16x32_bf16(aF[m], bF[n], acc[m][n], 0, 0, 0);
    }

    #pragma unroll
    for (int n = 0; n < 4; ++n) {
        int col = bcol + wc * 64 + n * 16 + (l & 15);
        float bn = bp[col];
        #pragma unroll
        for (int m = 0; m < M4; ++m) {
            int row0 = arow + wr * (BM / 2) + m * 16 + (l >> 4) * 4;
            #pragma unroll
            for (int j = 0; j < 4; ++j) {
                int row = row0 + j;
                float v = acc[m][n][j] + bn;
                if (MODE == 0) {
                    if (z == 0) v *= 0.125f * LOG2E;  // 1/sqrt(D) with log2e folded
                    int b = row >> 11, s = row & 2047, hh = col >> 6, d = col & 63;
                    OutB[zoff + (size_t)(((b * Hh) + hh) * Ss + s) * Dd + d] = f32_bf16(v);
                } else {
                    OutF[(size_t)row * N + col] = v;
                }
            }
        }
    }
}

// ---------------- V head-split transpose: [B,H,S,D] -> [B,H,D,S] ----------------
__global__ __launch_bounds__(256) void vtr_kernel(
    const uint16_t* __restrict__ src, uint16_t* __restrict__ dst)
{
    __shared__ uint32_t T32[64][33];
    const int tid = threadIdx.x;
    const int bh = blockIdx.y;
    const int s0 = blockIdx.x * 64;
    const uint16_t* S = src + ((size_t)bh * Ss + s0) * Dd;
    {
        int rp = tid >> 3, d8 = tid & 7;
        uint4 a = *(const uint4*)(S + (size_t)(2 * rp) * Dd + d8 * 8);
        uint4 b = *(const uint4*)(S + (size_t)(2 * rp + 1) * Dd + d8 * 8);
        const uint16_t* ea = (const uint16_t*)&a;
        const uint16_t* eb = (const uint16_t*)&b;
        #pragma unroll
        for (int e = 0; e < 8; ++e)
            T32[d8 * 8 + e][rp] = (uint32_t)ea[e] | ((uint32_t)eb[e] << 16);
    }
    __syncthreads();
    uint16_t* Dp = dst + (size_t)bh * Dd * Ss + s0;
    {
        int d = tid >> 3, rpc = (tid & 7) * 4;
        #pragma unroll
        for (int half = 0; half < 2; ++half) {
            int dd = d + 32 * half;
            union { uint32_t u[4]; uint4 v; } pk;
            #pragma unroll
            for (int j = 0; j < 4; ++j) pk.u[j] = T32[dd][rpc + j];
            *(uint4*)(Dp + (size_t)dd * Ss + rpc * 2) = pk.v;
        }
    }
}

// ---------------- flash attention: T15 pipeline — QK(t+1) overlaps softmax(t) ----
// Grid 512 = 16 qb x 32 bh (XCD-swizzled) = 2 blocks/CU. 4 waves x 32 q-rows.
// Tri-buffered LDS; per iter: vmcnt(0)+barrier -> stage(t+2) DMA ->
// {build_pb(s_cur) [VALU] || QK(t+1) [MFMA]} -> PV(t). Dual lsum accumulators
// halve the serial add chain; merged once at the end.
__global__ __launch_bounds__(256, 2) void attn_kernel(
    const uint16_t* __restrict__ Qh, const uint16_t* __restrict__ Kh,
    const uint16_t* __restrict__ Vtg, uint16_t* __restrict__ Ob)
{
    const int tid = threadIdx.x;
    const int l = tid & 63, w = tid >> 6;
    const int q = l & 31, hi = l >> 5;

    const int orig = blockIdx.x;
    const int L = (orig & 7) * 64 + (orig >> 3);
    const int qb = L & 15, bh = L >> 4;

    const int q0 = qb * 128;
    const size_t baseK = (size_t)bh * Ss * Dd;
    const size_t baseV = (size_t)bh * Dd * Ss;

    __shared__ alignas(16) uint16_t Ks[3][64 * 64];  // [key][d], XOR-swizzled
    __shared__ alignas(16) uint16_t Vt[3][64 * 64];  // [d][key], XOR-swizzled

    bf16x8 qf[4];
    {
        const uint16_t* qp = Qh + baseK + (size_t)(q0 + w * 32 + q) * Dd + hi * 8;
        #pragma unroll
        for (int m = 0; m < 4; ++m) qf[m] = *(const bf16x8*)(qp + 16 * m);
    }

    auto stage = [&](int kt, int buf) {
        const int key0 = kt * 64;
        #pragma unroll
        for (int it = 0; it < 2; ++it) {
            int c = tid + 256 * it, row = c >> 3, cc = c & 7;
            const uint16_t* gk = Kh + baseK + (size_t)(key0 + row) * Dd + ((cc ^ (row & 7)) * 8);
            __builtin_amdgcn_global_load_lds(
                (const __attribute__((address_space(1))) void*)gk,
                (__attribute__((address_space(3))) void*)(&Ks[buf][c * 8]), 16, 0, 0);
        }
        #pragma unroll
        for (int it = 0; it < 2; ++it) {
            int c = tid + 256 * it, d = c >> 3, j = c & 7;
            const uint16_t* gv = Vtg + baseV + (size_t)d * Ss + key0 + 8 * (j ^ (d & 7) ^ (d >> 3));
            __builtin_amdgcn_global_load_lds(
                (const __attribute__((address_space(1))) void*)gv,
                (__attribute__((address_space(3))) void*)(&Vt[buf][c * 8]), 16, 0, 0);
        }
    };

    f32x16 o0 = {}, o1 = {};
    float lsumA = 0.f, lsumB = 0.f;

    auto qk = [&](int b, f32x16& s0, f32x16& s1) {
        __builtin_amdgcn_s_setprio(1);
        #pragma unroll
        for (int m = 0; m < 4; ++m) {
            int sw = ((2 * m + hi) ^ (q & 7)) << 3;
            bf16x8 k0 = *(const bf16x8*)&Ks[b][q * 64 + sw];
            bf16x8 k1 = *(const bf16x8*)&Ks[b][(32 + q) * 64 + sw];
            s0 = __builtin_amdgcn_mfma_f32_32x32x16_bf16(k0, qf[m], s0, 0, 0, 0);
            s1 = __builtin_amdgcn_mfma_f32_32x32x16_bf16(k1, qf[m], s1, 0, 0, 0);
        }
        __builtin_amdgcn_s_setprio(0);
    };

    auto build_pb = [&](const f32x16& sv, bf16x8* pbout, float& lsum) {
        uint32_t W[4][2];
        #pragma unroll
        for (int a = 0; a < 4; ++a) {
            float p0 = __builtin_amdgcn_exp2f(sv[4 * a + 0]);
            float p1 = __builtin_amdgcn_exp2f(sv[4 * a + 1]);
            float p2 = __builtin_amdgcn_exp2f(sv[4 * a + 2]);
            float p3 = __builtin_amdgcn_exp2f(sv[4 * a + 3]);
            lsum += (p0 + p1) + (p2 + p3);
            W[a][0] = cvt_pk_bf16(p0, p1);
            W[a][1] = cvt_pk_bf16(p2, p3);
        }
        #pragma unroll
        for (int kl = 0; kl < 2; ++kl) {
            uint32_t x0 = W[2 * kl][0], x1 = W[2 * kl][1];
            uint32_t y0 = W[2 * kl + 1][0], y1 = W[2 * kl + 1][1];
            perm32swap(x0, y0);
            perm32swap(x1, y1);
            union { uint32_t u[4]; bf16x8 v; } pu;
            pu.u[0] = x0; pu.u[1] = x1; pu.u[2] = y0; pu.u[3] = y1;
            pbout[kl] = pu.v;
        }
    };

    auto pv = [&](int b, const bf16x8* pb) {
        __builtin_amdgcn_s_setprio(1);
        #pragma unroll
        for (int ka = 0; ka < 4; ++ka) {
            #pragma unroll
            for (int dt = 0; dt < 2; ++dt) {
                int d = 32 * dt + q;
                int swz = (2 * ka + hi) ^ (d & 7) ^ (d >> 3);
                bf16x8 vf = *(const bf16x8*)&Vt[b][d * 64 + swz * 8];
                if (dt == 0)
                    o0 = __builtin_amdgcn_mfma_f32_32x32x16_bf16(vf, pb[ka], o0, 0, 0, 0);
                else
                    o1 = __builtin_amdgcn_mfma_f32_32x32x16_bf16(vf, pb[ka], o1, 0, 0, 0);
            }
        }
        __builtin_amdgcn_s_setprio(0);
    };

    // prologue: tiles 0,1 staged; compute s(0)
    stage(0, 0);
    stage(1, 1);
    f32x16 sc0 = {}, sc1 = {};
    asm volatile("s_waitcnt vmcnt(4)" ::: "memory");   // stage(0) landed
    __builtin_amdgcn_s_barrier();
    __builtin_amdgcn_sched_barrier(0);
    qk(0, sc0, sc1);

    auto body = [&](int kt, int b, int bn, int bs, bool doStage, bool doNext) {
        asm volatile("s_waitcnt vmcnt(0)" ::: "memory");   // stage(kt+1) landed
        __builtin_amdgcn_s_barrier();                      // closes iter kt-1 reads
        __builtin_amdgcn_sched_barrier(0);
        if (doStage) stage(kt + 2, bs);

        bf16x8 pb[4];
        build_pb(sc0, pb + 0, lsumA);
        build_pb(sc1, pb + 2, lsumB);

        f32x16 sn0 = {}, sn1 = {};
        if (doNext) qk(bn, sn0, sn1);

        pv(b, pb);
        sc0 = sn0; sc1 = sn1;
    };

    for (int u = 0; u < 30; u += 3) {
        body(u + 0, 0, 1, 2, true, true);
        body(u + 1, 1, 2, 0, true, true);
        body(u + 2, 2, 0, 1, true, true);
    }
    body(30, 0, 1, 0, false, true);
    body(31, 1, 0, 0, false, false);

    // normalize + LDS transpose epilogue (reuse Ks[0..1]: 16 KB [q=128][d=64])
    float lsum = lsumA + lsumB;
    float lr = lsum + __shfl_xor(lsum, 32);
    const float inv = 1.0f / lr;
    __syncthreads();   // all waves done with tile-31 reads
    uint16_t* Os = &Ks[0][0];
    const int ql = w * 32 + q;
    #pragma unroll
    for (int dt = 0; dt < 2; ++dt) {
        const f32x16& oo = dt ? o1 : o0;
        #pragma unroll
        for (int rr = 0; rr < 16; ++rr) {
            int d = 32 * dt + (rr & 3) + 8 * (rr >> 2) + 4 * hi;
            Os[ql * 64 + (((d >> 3) ^ (ql & 7)) << 3) + (d & 7)] = f32_bf16(oo[rr] * inv);
        }
    }
    __syncthreads();
    const int bq = bh >> 4, hh = bh & 15;
    #pragma unroll
    for (int it = 0; it < 4; ++it) {
        int qr = it * 32 + (tid >> 3);
        int c = tid & 7;
        bf16x8 vv = *(const bf16x8*)&Os[qr * 64 + ((c ^ (qr & 7)) << 3)];
        *(bf16x8*)(Ob + (size_t)(bq * Ss + q0 + qr) * Ee + hh * Dd + c * 8) = vv;
    }
}

extern "C" void kernel_launch(void* const* d_in, const int* in_sizes, int n_in,
                              void* d_out, int out_size, void* d_ws, size_t ws_size,
                              hipStream_t stream) {
    (void)in_sizes; (void)n_in; (void)out_size; (void)ws_size;
    const float* query = (const float*)d_in[0];
    const float* key   = (const float*)d_in[1];
    const float* value = (const float*)d_in[2];
    const float* w_in  = (const float*)d_in[3];
    const float* b_in  = (const float*)d_in[4];
    const float* w_out = (const float*)d_in[5];
    const float* b_out = (const float*)d_in[6];
    uint16_t* ws = (uint16_t*)d_ws;

    uint16_t* qb    = ws + OFF_QB;
    uint16_t* kb    = ws + OFF_KB;
    uint16_t* vb    = ws + OFF_VB;
    uint16_t* wqkvb = ws + OFF_WQKV;
    uint16_t* woutb = ws + OFF_WOUT;
    uint16_t* Qh    = ws + OFF_QH;
    uint16_t* Kh    = ws + OFF_KH;
    uint16_t* Vtg   = ws + OFF_VH;
    uint16_t* Vsd   = ws + OFF_OB;             // z=2 staging [B,H,S,D]
    uint16_t* Ob    = ws + OFF_OB;

    cvt_kernel<<<dim3(4096, 1, 5), 256, 0, stream>>>(query, key, value, w_in, w_out, ws);
    gemm_nt<0, 128><<<dim3(8, 32, 3), 256, 0, stream>>>(qb, kb, vb, wqkvb, b_in, Qh, nullptr);
    vtr_kernel<<<dim3(32, 32), 256, 0, stream>>>(Vsd, Vtg);
    attn_kernel<<<dim3(512), 256, 0, stream>>>(Qh, Kh, Vtg, Ob);
    gemm_nt<1, 64><<<dim3(8, 64), 256, 0, stream>>>(Ob, nullptr, nullptr, woutb, b_out, nullptr, (float*)d_out);
}